// Round 1
// baseline (1722.944 us; speedup 1.0000x reference)
//
#include <hip/hip_runtime.h>
#include <hip/hip_bf16.h>

#define N_NODES 100000
#define E_EDGES 1250000
#define INC 64
#define HIDC 128
#define OUTC 64
#define K_ITERS 10
#define ALPHA 0.1f

// ---------------------------------------------------------------------------
// init: S[i][0:64] = x[i] (self loop contribution), S[i][64:128] = 0, cnt=1
// ---------------------------------------------------------------------------
__global__ __launch_bounds__(256) void init_kernel(const float* __restrict__ x,
                                                   float* __restrict__ S,
                                                   float* __restrict__ cntRow) {
    int idx = blockIdx.x * 256 + threadIdx.x;
    if (idx >= N_NODES * 64) return;
    int n = idx >> 6, f = idx & 63;
    S[(size_t)n * 128 + f] = x[(size_t)n * 64 + f];
    S[(size_t)n * 128 + 64 + f] = 0.0f;
    if (f == 0) cntRow[n] = 1.0f;
}

// ---------------------------------------------------------------------------
// edge accumulate: for edge e (row=ei0, col=ei1):
//   S[row][0:64]   += x[col]        (feeds W_node after fold)
//   S[row][64:128] += edge_attr[e]  (feeds W_edge after fold)
//   cntRow[row] += 1;  degDst[col] += 1  (APPNP degree histogram)
// one wave (64 lanes) per edge, grid-stride
// ---------------------------------------------------------------------------
__global__ __launch_bounds__(256) void edge_accum(const float* __restrict__ x,
                                                  const float* __restrict__ ea,
                                                  const int* __restrict__ ei,
                                                  float* __restrict__ S,
                                                  float* __restrict__ cntRow,
                                                  int* __restrict__ degDst) {
    int wave = (blockIdx.x * 256 + threadIdx.x) >> 6;
    int lane = threadIdx.x & 63;
    int nwaves = (gridDim.x * 256) >> 6;
    for (int e = wave; e < E_EDGES; e += nwaves) {
        int row = ei[e];
        int col = ei[E_EDGES + e];
        float a = ea[(size_t)e * 64 + lane];
        atomicAdd(&S[(size_t)row * 128 + 64 + lane], a);
        float xv = x[(size_t)col * 64 + lane];
        atomicAdd(&S[(size_t)row * 128 + lane], xv);
        if (lane == 0) {
            atomicAdd(&cntRow[row], 1.0f);
            atomicAdd(&degDst[col], 1);
        }
    }
}

// ---------------------------------------------------------------------------
// dinv = rsqrt(deg+1)   (deg includes self loop)
// ---------------------------------------------------------------------------
__global__ __launch_bounds__(256) void dinv_kernel(const int* __restrict__ degDst,
                                                   float* __restrict__ dinv) {
    int i = blockIdx.x * 256 + threadIdx.x;
    if (i >= N_NODES) return;
    dinv[i] = rsqrtf((float)(degDst[i] + 1));
}

// ---------------------------------------------------------------------------
// 3-kernel exclusive scan of degDst -> rp (CSR row pointers by dst)
// ---------------------------------------------------------------------------
__global__ __launch_bounds__(256) void scan_block_sums(const int* __restrict__ degDst,
                                                       int* __restrict__ blockSums) {
    __shared__ int sh[256];
    int t = threadIdx.x;
    int i = blockIdx.x * 256 + t;
    sh[t] = (i < N_NODES) ? degDst[i] : 0;
    __syncthreads();
    for (int off = 128; off > 0; off >>= 1) {
        if (t < off) sh[t] += sh[t + off];
        __syncthreads();
    }
    if (t == 0) blockSums[blockIdx.x] = sh[0];
}

__global__ __launch_bounds__(512) void scan_top(const int* __restrict__ blockSums,
                                                int* __restrict__ blockScan, int nb) {
    __shared__ int sh[512];
    int t = threadIdx.x;
    int v = (t < nb) ? blockSums[t] : 0;
    sh[t] = v;
    __syncthreads();
    for (int off = 1; off < 512; off <<= 1) {
        int xv = (t >= off) ? sh[t - off] : 0;
        __syncthreads();
        sh[t] += xv;
        __syncthreads();
    }
    if (t < nb) blockScan[t] = sh[t] - v;  // exclusive
}

__global__ __launch_bounds__(256) void scan_write_rp(const int* __restrict__ degDst,
                                                     const int* __restrict__ blockScan,
                                                     int* __restrict__ rp) {
    __shared__ int sh[256];
    int t = threadIdx.x;
    int i = blockIdx.x * 256 + t;
    int v = (i < N_NODES) ? degDst[i] : 0;
    sh[t] = v;
    __syncthreads();
    for (int off = 1; off < 256; off <<= 1) {
        int xv = (t >= off) ? sh[t - off] : 0;
        __syncthreads();
        sh[t] += xv;
        __syncthreads();
    }
    if (i < N_NODES) rp[i] = blockScan[blockIdx.x] + (sh[t] - v);
    if (i == 0) rp[N_NODES] = E_EDGES;
}

// ---------------------------------------------------------------------------
// CSR scatter: slot edges under their dst, with precomputed norm weight
// ---------------------------------------------------------------------------
__global__ __launch_bounds__(256) void csr_scatter(const int* __restrict__ ei,
                                                   const float* __restrict__ dinv,
                                                   const int* __restrict__ rp,
                                                   int* __restrict__ cursor,
                                                   int* __restrict__ sidx,
                                                   float* __restrict__ wgt) {
    int e = blockIdx.x * 256 + threadIdx.x;
    if (e >= E_EDGES) return;
    int src = ei[e];
    int dst = ei[E_EDGES + e];
    int pos = rp[dst] + atomicAdd(&cursor[dst], 1);
    sidx[pos] = src;
    wgt[pos] = dinv[src] * dinv[dst];
}

// ---------------------------------------------------------------------------
// Fused GEMM: out = epilogue(A[N,128] @ W[128,NC])
// MODE 0: W = [W_node; W_edge] stacked, out = relu(acc/cnt + b_node + (1-1/cnt)*b_edge)
// MODE 1: out = relu(acc + b1)
// MODE 2: out = acc + b2
// 64 rows/block, 256 threads, K split in two 64-row W phases (LDS <= 64KB).
// In-place safe: A rows fully staged to LDS before epilogue writes.
// ---------------------------------------------------------------------------
template <int NC, int MODE>
__global__ __launch_bounds__(256) void gemm_k(const float* __restrict__ A,
                                              const float* __restrict__ Wa,
                                              const float* __restrict__ Wb,
                                              const float* __restrict__ ba,
                                              const float* __restrict__ bb,
                                              const float* __restrict__ cnt,
                                              float* __restrict__ out) {
    constexpr int CPT = NC / 16;  // cols per thread
    __shared__ float Al[64][128];
    __shared__ float Wl[64][NC];
    const int tid = threadIdx.x;
    const int rb = blockIdx.x * 64;

    for (int idx = tid; idx < 64 * 32; idx += 256) {
        int r = idx >> 5, c4 = idx & 31;
        int gr = rb + r;
        float4 v = make_float4(0.f, 0.f, 0.f, 0.f);
        if (gr < N_NODES) v = *reinterpret_cast<const float4*>(A + (size_t)gr * 128 + c4 * 4);
        *reinterpret_cast<float4*>(&Al[r][c4 * 4]) = v;
    }

    const int trow = tid >> 4, tcol = tid & 15;
    float acc[4][CPT];
#pragma unroll
    for (int q = 0; q < 4; q++)
#pragma unroll
        for (int j = 0; j < CPT; j++) acc[q][j] = 0.f;

    for (int half = 0; half < 2; ++half) {
        __syncthreads();  // A loads done (half 0) / previous Wl reads done (half 1)
        for (int idx = tid; idx < 64 * (NC / 4); idx += 256) {
            int k = idx / (NC / 4), c4 = idx % (NC / 4);
            int gk = half * 64 + k;
            const float* src;
            if constexpr (MODE == 0) {
                src = (gk < 64) ? (Wa + (size_t)gk * NC + c4 * 4)
                                : (Wb + (size_t)(gk - 64) * NC + c4 * 4);
            } else {
                src = Wa + (size_t)gk * NC + c4 * 4;
            }
            *reinterpret_cast<float4*>(&Wl[k][c4 * 4]) = *reinterpret_cast<const float4*>(src);
        }
        __syncthreads();
#pragma unroll 4
        for (int k = 0; k < 64; k++) {
            float a0 = Al[trow][half * 64 + k];
            float a1 = Al[trow + 16][half * 64 + k];
            float a2 = Al[trow + 32][half * 64 + k];
            float a3 = Al[trow + 48][half * 64 + k];
#pragma unroll
            for (int j = 0; j < CPT; j++) {
                float w = Wl[k][tcol * CPT + j];
                acc[0][j] += a0 * w;
                acc[1][j] += a1 * w;
                acc[2][j] += a2 * w;
                acc[3][j] += a3 * w;
            }
        }
    }

#pragma unroll
    for (int q = 0; q < 4; q++) {
        int gr = rb + trow + 16 * q;
        if (gr >= N_NODES) continue;
        float inv = 0.f;
        if constexpr (MODE == 0) inv = 1.0f / cnt[gr];
#pragma unroll
        for (int j = 0; j < CPT; j++) {
            int c = tcol * CPT + j;
            float v = acc[q][j];
            if constexpr (MODE == 0) {
                v = v * inv + ba[c] + (1.0f - inv) * bb[c];
                v = fmaxf(v, 0.f);
            } else if constexpr (MODE == 1) {
                v = fmaxf(v + ba[c], 0.f);
            } else {
                v = v + ba[c];
            }
            out[(size_t)gr * NC + c] = v;
        }
    }
}

// ---------------------------------------------------------------------------
// APPNP step: out[i] = 0.9*( dinv[i]^2*h[i] + sum_e wgt*h[src] ) + 0.1*h0[i]
// one wave per node, lane = feature (OUTC == 64 == wave size)
// ---------------------------------------------------------------------------
__global__ __launch_bounds__(256) void appnp_step(const float* __restrict__ h,
                                                  const float* __restrict__ h0,
                                                  float* __restrict__ out,
                                                  const int* __restrict__ rp,
                                                  const int* __restrict__ sidx,
                                                  const float* __restrict__ wgt,
                                                  const float* __restrict__ dinv) {
    int wid = (blockIdx.x * 256 + threadIdx.x) >> 6;
    int lane = threadIdx.x & 63;
    if (wid >= N_NODES) return;
    float di = dinv[wid];
    float acc = di * di * h[(size_t)wid * 64 + lane];
    int e = rp[wid], eend = rp[wid + 1];
    for (; e + 1 < eend; e += 2) {
        int s0 = sidx[e], s1 = sidx[e + 1];
        float w0 = wgt[e], w1 = wgt[e + 1];
        float v0 = h[(size_t)s0 * 64 + lane];
        float v1 = h[(size_t)s1 * 64 + lane];
        acc += w0 * v0 + w1 * v1;
    }
    if (e < eend) acc += wgt[e] * h[(size_t)sidx[e] * 64 + lane];
    out[(size_t)wid * 64 + lane] = (1.0f - ALPHA) * acc + ALPHA * h0[(size_t)wid * 64 + lane];
}

// ---------------------------------------------------------------------------
extern "C" void kernel_launch(void* const* d_in, const int* in_sizes, int n_in,
                              void* d_out, int out_size, void* d_ws, size_t ws_size,
                              hipStream_t stream) {
    const float* x      = (const float*)d_in[0];
    const float* eattr  = (const float*)d_in[1];
    const float* W_node = (const float*)d_in[2];
    const float* b_node = (const float*)d_in[3];
    const float* W_edge = (const float*)d_in[4];
    const float* b_edge = (const float*)d_in[5];
    const float* W1     = (const float*)d_in[6];
    const float* b1     = (const float*)d_in[7];
    const float* W2     = (const float*)d_in[8];
    const float* b2     = (const float*)d_in[9];
    const int*   ei     = (const int*)d_in[10];
    float* out = (float*)d_out;

    char* ws = (char*)d_ws;
    size_t off = 0;
    auto alloc = [&](size_t bytes) -> void* {
        void* p = ws + off;
        off += (bytes + 511) & ~(size_t)511;
        return p;
    };
    float* buf0   = (float*)alloc((size_t)N_NODES * 128 * 4);  // S / x_enh / h_mid / hA|hB
    float* h0     = (float*)alloc((size_t)N_NODES * 64 * 4);
    float* cntRow = (float*)alloc((size_t)N_NODES * 4);
    int*   degDst = (int*)alloc((size_t)N_NODES * 4);
    float* dinv   = (float*)alloc((size_t)N_NODES * 4);
    int*   rp     = (int*)alloc((size_t)(N_NODES + 1) * 4);
    int*   cursor = (int*)alloc((size_t)N_NODES * 4);
    int*   sidx   = (int*)alloc((size_t)E_EDGES * 4);
    float* wgt    = (float*)alloc((size_t)E_EDGES * 4);
    int*   blockSums = (int*)alloc(512 * 4);
    int*   blockScan = (int*)alloc(512 * 4);

    constexpr int NB = (N_NODES + 255) / 256;  // 391 scan chunks

    hipMemsetAsync(degDst, 0, (size_t)N_NODES * 4, stream);
    hipMemsetAsync(cursor, 0, (size_t)N_NODES * 4, stream);

    init_kernel<<<(N_NODES * 64 + 255) / 256, 256, 0, stream>>>(x, buf0, cntRow);
    edge_accum<<<2048, 256, 0, stream>>>(x, eattr, ei, buf0, cntRow, degDst);
    dinv_kernel<<<(N_NODES + 255) / 256, 256, 0, stream>>>(degDst, dinv);
    scan_block_sums<<<NB, 256, 0, stream>>>(degDst, blockSums);
    scan_top<<<1, 512, 0, stream>>>(blockSums, blockScan, NB);
    scan_write_rp<<<NB, 256, 0, stream>>>(degDst, blockScan, rp);
    csr_scatter<<<(E_EDGES + 255) / 256, 256, 0, stream>>>(ei, dinv, rp, cursor, sidx, wgt);

    gemm_k<128, 0><<<(N_NODES + 63) / 64, 256, 0, stream>>>(buf0, W_node, W_edge, b_node, b_edge, cntRow, buf0);
    gemm_k<128, 1><<<(N_NODES + 63) / 64, 256, 0, stream>>>(buf0, W1, nullptr, b1, nullptr, nullptr, buf0);
    gemm_k<64, 2><<<(N_NODES + 63) / 64, 256, 0, stream>>>(buf0, W2, nullptr, b2, nullptr, nullptr, h0);

    float* hA = buf0;
    float* hB = buf0 + (size_t)N_NODES * 64;
    const float* hcur = h0;
    for (int k = 0; k < K_ITERS; k++) {
        float* dst = (k == K_ITERS - 1) ? out : ((k & 1) ? hB : hA);
        appnp_step<<<(N_NODES * 64 + 255) / 256, 256, 0, stream>>>(hcur, h0, dst, rp, sidx, wgt, dinv);
        hcur = dst;
    }
}

// Round 2
// 1404.949 us; speedup vs baseline: 1.2263x; 1.2263x over previous
//
#include <hip/hip_runtime.h>
#include <hip/hip_bf16.h>

#define N_NODES 100000
#define E_EDGES 1250000
#define INC 64
#define HIDC 128
#define OUTC 64
#define K_ITERS 10
#define ALPHA 0.1f

// ---------------------------------------------------------------------------
// histograms: degRow[ei0]++ (enhancement CSR), degDst[ei1]++ (APPNP CSR)
// ---------------------------------------------------------------------------
__global__ __launch_bounds__(256) void hist2(const int* __restrict__ ei,
                                             int* __restrict__ degRow,
                                             int* __restrict__ degDst) {
    int e = blockIdx.x * 256 + threadIdx.x;
    if (e >= E_EDGES) return;
    atomicAdd(&degRow[ei[e]], 1);
    atomicAdd(&degDst[ei[E_EDGES + e]], 1);
}

// ---------------------------------------------------------------------------
// dinv = rsqrt(degDst+1)   (deg includes self loop)
// ---------------------------------------------------------------------------
__global__ __launch_bounds__(256) void dinv_kernel(const int* __restrict__ degDst,
                                                   float* __restrict__ dinv) {
    int i = blockIdx.x * 256 + threadIdx.x;
    if (i >= N_NODES) return;
    dinv[i] = rsqrtf((float)(degDst[i] + 1));
}

// ---------------------------------------------------------------------------
// 3-kernel exclusive scan of deg -> rp (CSR row pointers)
// ---------------------------------------------------------------------------
__global__ __launch_bounds__(256) void scan_block_sums(const int* __restrict__ deg,
                                                       int* __restrict__ blockSums) {
    __shared__ int sh[256];
    int t = threadIdx.x;
    int i = blockIdx.x * 256 + t;
    sh[t] = (i < N_NODES) ? deg[i] : 0;
    __syncthreads();
    for (int off = 128; off > 0; off >>= 1) {
        if (t < off) sh[t] += sh[t + off];
        __syncthreads();
    }
    if (t == 0) blockSums[blockIdx.x] = sh[0];
}

__global__ __launch_bounds__(512) void scan_top(const int* __restrict__ blockSums,
                                                int* __restrict__ blockScan, int nb) {
    __shared__ int sh[512];
    int t = threadIdx.x;
    int v = (t < nb) ? blockSums[t] : 0;
    sh[t] = v;
    __syncthreads();
    for (int off = 1; off < 512; off <<= 1) {
        int xv = (t >= off) ? sh[t - off] : 0;
        __syncthreads();
        sh[t] += xv;
        __syncthreads();
    }
    if (t < nb) blockScan[t] = sh[t] - v;  // exclusive
}

__global__ __launch_bounds__(256) void scan_write_rp(const int* __restrict__ deg,
                                                     const int* __restrict__ blockScan,
                                                     int* __restrict__ rp) {
    __shared__ int sh[256];
    int t = threadIdx.x;
    int i = blockIdx.x * 256 + t;
    int v = (i < N_NODES) ? deg[i] : 0;
    sh[t] = v;
    __syncthreads();
    for (int off = 1; off < 256; off <<= 1) {
        int xv = (t >= off) ? sh[t - off] : 0;
        __syncthreads();
        sh[t] += xv;
        __syncthreads();
    }
    if (i < N_NODES) rp[i] = blockScan[blockIdx.x] + (sh[t] - v);
    if (i == 0) rp[N_NODES] = E_EDGES;
}

// ---------------------------------------------------------------------------
// scatter into BOTH CSRs:
//  enhancement CSR (key=ei0): cidx[pos]=ei1 (x gather index), eid[pos]=e
//  APPNP CSR       (key=ei1): sidx[pos]=ei0, wgt[pos]=dinv[ei0]*dinv[ei1]
// ---------------------------------------------------------------------------
__global__ __launch_bounds__(256) void scatter_both(const int* __restrict__ ei,
                                                    const float* __restrict__ dinv,
                                                    const int* __restrict__ rpRow,
                                                    const int* __restrict__ rpDst,
                                                    int* __restrict__ curRow,
                                                    int* __restrict__ curDst,
                                                    int* __restrict__ cidx,
                                                    int* __restrict__ eid,
                                                    int* __restrict__ sidx,
                                                    float* __restrict__ wgt) {
    int e = blockIdx.x * 256 + threadIdx.x;
    if (e >= E_EDGES) return;
    int r0 = ei[e];            // row / src
    int r1 = ei[E_EDGES + e];  // col / dst
    int pr = rpRow[r0] + atomicAdd(&curRow[r0], 1);
    cidx[pr] = r1;
    eid[pr] = e;
    int pd = rpDst[r1] + atomicAdd(&curDst[r1], 1);
    sidx[pd] = r0;
    wgt[pd] = dinv[r0] * dinv[r1];
}

// ---------------------------------------------------------------------------
// aggregate (gather, no atomics): one wave per node, lane = feature
//   S[n][0:64]   = x[n] + sum_j x[cidx[j]]
//   S[n][64:128] = sum_j edge_attr[eid[j]]
//   cntRow[n]    = deg+1
// ---------------------------------------------------------------------------
__global__ __launch_bounds__(256) void aggregate(const float* __restrict__ x,
                                                 const float* __restrict__ ea,
                                                 const int* __restrict__ rpRow,
                                                 const int* __restrict__ cidx,
                                                 const int* __restrict__ eid,
                                                 float* __restrict__ S,
                                                 float* __restrict__ cntRow) {
    int wid = (blockIdx.x * 256 + threadIdx.x) >> 6;
    int lane = threadIdx.x & 63;
    if (wid >= N_NODES) return;
    int jb = rpRow[wid], je = rpRow[wid + 1];
    float accx = x[(size_t)wid * 64 + lane];  // self loop
    float acce = 0.0f;
    int j = jb;
    for (; j + 1 < je; j += 2) {
        int c0 = cidx[j], c1 = cidx[j + 1];
        int e0 = eid[j], e1 = eid[j + 1];
        float xv0 = x[(size_t)c0 * 64 + lane];
        float av0 = ea[(size_t)e0 * 64 + lane];
        float xv1 = x[(size_t)c1 * 64 + lane];
        float av1 = ea[(size_t)e1 * 64 + lane];
        accx += xv0 + xv1;
        acce += av0 + av1;
    }
    if (j < je) {
        accx += x[(size_t)cidx[j] * 64 + lane];
        acce += ea[(size_t)eid[j] * 64 + lane];
    }
    S[(size_t)wid * 128 + lane] = accx;
    S[(size_t)wid * 128 + 64 + lane] = acce;
    if (lane == 0) cntRow[wid] = (float)(je - jb + 1);
}

// ---------------------------------------------------------------------------
// Fused GEMM: out = epilogue(A[N,128] @ W[128,NC])
// MODE 0: W = [W_node; W_edge] stacked, out = relu(acc/cnt + b_node + (1-1/cnt)*b_edge)
// MODE 1: out = relu(acc + b1)
// MODE 2: out = acc + b2
// ---------------------------------------------------------------------------
template <int NC, int MODE>
__global__ __launch_bounds__(256) void gemm_k(const float* __restrict__ A,
                                              const float* __restrict__ Wa,
                                              const float* __restrict__ Wb,
                                              const float* __restrict__ ba,
                                              const float* __restrict__ bb,
                                              const float* __restrict__ cnt,
                                              float* __restrict__ out) {
    constexpr int CPT = NC / 16;  // cols per thread
    __shared__ float Al[64][128];
    __shared__ float Wl[64][NC];
    const int tid = threadIdx.x;
    const int rb = blockIdx.x * 64;

    for (int idx = tid; idx < 64 * 32; idx += 256) {
        int r = idx >> 5, c4 = idx & 31;
        int gr = rb + r;
        float4 v = make_float4(0.f, 0.f, 0.f, 0.f);
        if (gr < N_NODES) v = *reinterpret_cast<const float4*>(A + (size_t)gr * 128 + c4 * 4);
        *reinterpret_cast<float4*>(&Al[r][c4 * 4]) = v;
    }

    const int trow = tid >> 4, tcol = tid & 15;
    float acc[4][CPT];
#pragma unroll
    for (int q = 0; q < 4; q++)
#pragma unroll
        for (int j = 0; j < CPT; j++) acc[q][j] = 0.f;

    for (int half = 0; half < 2; ++half) {
        __syncthreads();
        for (int idx = tid; idx < 64 * (NC / 4); idx += 256) {
            int k = idx / (NC / 4), c4 = idx % (NC / 4);
            int gk = half * 64 + k;
            const float* src;
            if constexpr (MODE == 0) {
                src = (gk < 64) ? (Wa + (size_t)gk * NC + c4 * 4)
                                : (Wb + (size_t)(gk - 64) * NC + c4 * 4);
            } else {
                src = Wa + (size_t)gk * NC + c4 * 4;
            }
            *reinterpret_cast<float4*>(&Wl[k][c4 * 4]) = *reinterpret_cast<const float4*>(src);
        }
        __syncthreads();
#pragma unroll 4
        for (int k = 0; k < 64; k++) {
            float a0 = Al[trow][half * 64 + k];
            float a1 = Al[trow + 16][half * 64 + k];
            float a2 = Al[trow + 32][half * 64 + k];
            float a3 = Al[trow + 48][half * 64 + k];
#pragma unroll
            for (int j = 0; j < CPT; j++) {
                float w = Wl[k][tcol * CPT + j];
                acc[0][j] += a0 * w;
                acc[1][j] += a1 * w;
                acc[2][j] += a2 * w;
                acc[3][j] += a3 * w;
            }
        }
    }

#pragma unroll
    for (int q = 0; q < 4; q++) {
        int gr = rb + trow + 16 * q;
        if (gr >= N_NODES) continue;
        float inv = 0.f;
        if constexpr (MODE == 0) inv = 1.0f / cnt[gr];
#pragma unroll
        for (int j = 0; j < CPT; j++) {
            int c = tcol * CPT + j;
            float v = acc[q][j];
            if constexpr (MODE == 0) {
                v = v * inv + ba[c] + (1.0f - inv) * bb[c];
                v = fmaxf(v, 0.f);
            } else if constexpr (MODE == 1) {
                v = fmaxf(v + ba[c], 0.f);
            } else {
                v = v + ba[c];
            }
            out[(size_t)gr * NC + c] = v;
        }
    }
}

// ---------------------------------------------------------------------------
// APPNP step: out[i] = 0.9*( dinv[i]^2*h[i] + sum_e wgt*h[src] ) + 0.1*h0[i]
// ---------------------------------------------------------------------------
__global__ __launch_bounds__(256) void appnp_step(const float* __restrict__ h,
                                                  const float* __restrict__ h0,
                                                  float* __restrict__ out,
                                                  const int* __restrict__ rp,
                                                  const int* __restrict__ sidx,
                                                  const float* __restrict__ wgt,
                                                  const float* __restrict__ dinv) {
    int wid = (blockIdx.x * 256 + threadIdx.x) >> 6;
    int lane = threadIdx.x & 63;
    if (wid >= N_NODES) return;
    float di = dinv[wid];
    float acc = di * di * h[(size_t)wid * 64 + lane];
    int e = rp[wid], eend = rp[wid + 1];
    for (; e + 1 < eend; e += 2) {
        int s0 = sidx[e], s1 = sidx[e + 1];
        float w0 = wgt[e], w1 = wgt[e + 1];
        float v0 = h[(size_t)s0 * 64 + lane];
        float v1 = h[(size_t)s1 * 64 + lane];
        acc += w0 * v0 + w1 * v1;
    }
    if (e < eend) acc += wgt[e] * h[(size_t)sidx[e] * 64 + lane];
    out[(size_t)wid * 64 + lane] = (1.0f - ALPHA) * acc + ALPHA * h0[(size_t)wid * 64 + lane];
}

// ---------------------------------------------------------------------------
extern "C" void kernel_launch(void* const* d_in, const int* in_sizes, int n_in,
                              void* d_out, int out_size, void* d_ws, size_t ws_size,
                              hipStream_t stream) {
    const float* x      = (const float*)d_in[0];
    const float* eattr  = (const float*)d_in[1];
    const float* W_node = (const float*)d_in[2];
    const float* b_node = (const float*)d_in[3];
    const float* W_edge = (const float*)d_in[4];
    const float* b_edge = (const float*)d_in[5];
    const float* W1     = (const float*)d_in[6];
    const float* b1     = (const float*)d_in[7];
    const float* W2     = (const float*)d_in[8];
    const float* b2     = (const float*)d_in[9];
    const int*   ei     = (const int*)d_in[10];
    float* out = (float*)d_out;

    char* ws = (char*)d_ws;
    size_t off = 0;
    auto alloc = [&](size_t bytes) -> void* {
        void* p = ws + off;
        off += (bytes + 511) & ~(size_t)511;
        return p;
    };
    float* buf0   = (float*)alloc((size_t)N_NODES * 128 * 4);  // S / x_enh / h_mid / hA|hB
    float* h0     = (float*)alloc((size_t)N_NODES * 64 * 4);   // also hosts cidx,eid early
    float* cntRow = (float*)alloc((size_t)N_NODES * 4);
    int*   degRow = (int*)alloc((size_t)N_NODES * 4);
    int*   degDst = (int*)alloc((size_t)N_NODES * 4);
    float* dinv   = (float*)alloc((size_t)N_NODES * 4);
    int*   rpRow  = (int*)alloc((size_t)(N_NODES + 1) * 4);
    int*   rpDst  = (int*)alloc((size_t)(N_NODES + 1) * 4);
    int*   curRow = (int*)alloc((size_t)N_NODES * 4);
    int*   curDst = (int*)alloc((size_t)N_NODES * 4);
    int*   sidx   = (int*)alloc((size_t)E_EDGES * 4);
    float* wgt    = (float*)alloc((size_t)E_EDGES * 4);
    int*   blockSums = (int*)alloc(512 * 4);
    int*   blockScan = (int*)alloc(512 * 4);

    // cidx/eid alias the h0 region: dead before h0 is first written (gemm2)
    int* cidx = (int*)h0;
    int* eid  = cidx + E_EDGES;

    constexpr int NB = (N_NODES + 255) / 256;  // 391 scan chunks

    hipMemsetAsync(degRow, 0, (size_t)N_NODES * 4, stream);
    hipMemsetAsync(degDst, 0, (size_t)N_NODES * 4, stream);
    hipMemsetAsync(curRow, 0, (size_t)N_NODES * 4, stream);
    hipMemsetAsync(curDst, 0, (size_t)N_NODES * 4, stream);

    hist2<<<(E_EDGES + 255) / 256, 256, 0, stream>>>(ei, degRow, degDst);
    dinv_kernel<<<(N_NODES + 255) / 256, 256, 0, stream>>>(degDst, dinv);

    scan_block_sums<<<NB, 256, 0, stream>>>(degRow, blockSums);
    scan_top<<<1, 512, 0, stream>>>(blockSums, blockScan, NB);
    scan_write_rp<<<NB, 256, 0, stream>>>(degRow, blockScan, rpRow);

    scan_block_sums<<<NB, 256, 0, stream>>>(degDst, blockSums);
    scan_top<<<1, 512, 0, stream>>>(blockSums, blockScan, NB);
    scan_write_rp<<<NB, 256, 0, stream>>>(degDst, blockScan, rpDst);

    scatter_both<<<(E_EDGES + 255) / 256, 256, 0, stream>>>(ei, dinv, rpRow, rpDst,
                                                            curRow, curDst, cidx, eid,
                                                            sidx, wgt);

    aggregate<<<(N_NODES + 3) / 4, 256, 0, stream>>>(x, eattr, rpRow, cidx, eid, buf0, cntRow);

    gemm_k<128, 0><<<(N_NODES + 63) / 64, 256, 0, stream>>>(buf0, W_node, W_edge, b_node, b_edge, cntRow, buf0);
    gemm_k<128, 1><<<(N_NODES + 63) / 64, 256, 0, stream>>>(buf0, W1, nullptr, b1, nullptr, nullptr, buf0);
    gemm_k<64, 2><<<(N_NODES + 63) / 64, 256, 0, stream>>>(buf0, W2, nullptr, b2, nullptr, nullptr, h0);

    float* hA = buf0;
    float* hB = buf0 + (size_t)N_NODES * 64;
    const float* hcur = h0;
    for (int k = 0; k < K_ITERS; k++) {
        float* dst = (k == K_ITERS - 1) ? out : ((k & 1) ? hB : hA);
        appnp_step<<<(N_NODES * 64 + 255) / 256, 256, 0, stream>>>(hcur, h0, dst, rpDst, sidx, wgt, dinv);
        hcur = dst;
    }
}

// Round 3
// 1193.759 us; speedup vs baseline: 1.4433x; 1.1769x over previous
//
#include <hip/hip_runtime.h>
#include <hip/hip_bf16.h>

#define N_NODES 100000
#define E_EDGES 1250000
#define INC 64
#define HIDC 128
#define OUTC 64
#define K_ITERS 10
#define ALPHA 0.1f

// ---------------------------------------------------------------------------
// histograms: degRow[ei0]++ (enhancement CSR), degDst[ei1]++ (APPNP CSR)
// ---------------------------------------------------------------------------
__global__ __launch_bounds__(256) void hist2(const int* __restrict__ ei,
                                             int* __restrict__ degRow,
                                             int* __restrict__ degDst) {
    int e = blockIdx.x * 256 + threadIdx.x;
    if (e >= E_EDGES) return;
    atomicAdd(&degRow[ei[e]], 1);
    atomicAdd(&degDst[ei[E_EDGES + e]], 1);
}

// ---------------------------------------------------------------------------
// dinv = rsqrt(degDst+1)   (deg includes self loop)
// ---------------------------------------------------------------------------
__global__ __launch_bounds__(256) void dinv_kernel(const int* __restrict__ degDst,
                                                   float* __restrict__ dinv) {
    int i = blockIdx.x * 256 + threadIdx.x;
    if (i >= N_NODES) return;
    dinv[i] = rsqrtf((float)(degDst[i] + 1));
}

// ---------------------------------------------------------------------------
// fused 2-array exclusive scan -> rpRow, rpDst  (grid.y / blockIdx.x selects array)
// ---------------------------------------------------------------------------
__global__ __launch_bounds__(256) void scan_block_sums2(const int* __restrict__ degRow,
                                                        const int* __restrict__ degDst,
                                                        int* __restrict__ blockSums) {
    const int* deg = blockIdx.y ? degDst : degRow;
    __shared__ int sh[256];
    int t = threadIdx.x;
    int i = blockIdx.x * 256 + t;
    sh[t] = (i < N_NODES) ? deg[i] : 0;
    __syncthreads();
    for (int off = 128; off > 0; off >>= 1) {
        if (t < off) sh[t] += sh[t + off];
        __syncthreads();
    }
    if (t == 0) blockSums[blockIdx.y * 512 + blockIdx.x] = sh[0];
}

__global__ __launch_bounds__(512) void scan_top2(const int* __restrict__ blockSums,
                                                 int* __restrict__ blockScan, int nb) {
    const int* bs = blockSums + blockIdx.x * 512;
    int* bo = blockScan + blockIdx.x * 512;
    __shared__ int sh[512];
    int t = threadIdx.x;
    int v = (t < nb) ? bs[t] : 0;
    sh[t] = v;
    __syncthreads();
    for (int off = 1; off < 512; off <<= 1) {
        int xv = (t >= off) ? sh[t - off] : 0;
        __syncthreads();
        sh[t] += xv;
        __syncthreads();
    }
    if (t < nb) bo[t] = sh[t] - v;  // exclusive
}

__global__ __launch_bounds__(256) void scan_write_rp2(const int* __restrict__ degRow,
                                                      const int* __restrict__ degDst,
                                                      const int* __restrict__ blockScan,
                                                      int* __restrict__ rpRow,
                                                      int* __restrict__ rpDst) {
    const int* deg = blockIdx.y ? degDst : degRow;
    int* rp = blockIdx.y ? rpDst : rpRow;
    __shared__ int sh[256];
    int t = threadIdx.x;
    int i = blockIdx.x * 256 + t;
    int v = (i < N_NODES) ? deg[i] : 0;
    sh[t] = v;
    __syncthreads();
    for (int off = 1; off < 256; off <<= 1) {
        int xv = (t >= off) ? sh[t - off] : 0;
        __syncthreads();
        sh[t] += xv;
        __syncthreads();
    }
    if (i < N_NODES) rp[i] = blockScan[blockIdx.y * 512 + blockIdx.x] + (sh[t] - v);
    if (i == 0) rp[N_NODES] = E_EDGES;
}

// ---------------------------------------------------------------------------
// scatter into BOTH CSRs (packed payloads):
//  enhancement CSR (key=ei0): ce[pos] = (col, edge_id)
//  APPNP CSR       (key=ei1): ew[pos] = (src, 0.9*dinv[src]*dinv[dst])
// ---------------------------------------------------------------------------
__global__ __launch_bounds__(256) void scatter_both(const int* __restrict__ ei,
                                                    const float* __restrict__ dinv,
                                                    const int* __restrict__ rpRow,
                                                    const int* __restrict__ rpDst,
                                                    int* __restrict__ curRow,
                                                    int* __restrict__ curDst,
                                                    int2* __restrict__ ce,
                                                    int2* __restrict__ ew) {
    int e = blockIdx.x * 256 + threadIdx.x;
    if (e >= E_EDGES) return;
    int r0 = ei[e];            // row / src
    int r1 = ei[E_EDGES + e];  // col / dst
    int pr = rpRow[r0] + atomicAdd(&curRow[r0], 1);
    ce[pr] = make_int2(r1, e);
    int pd = rpDst[r1] + atomicAdd(&curDst[r1], 1);
    float w = (1.0f - ALPHA) * dinv[r0] * dinv[r1];
    ew[pd] = make_int2(r0, __float_as_int(w));
}

// ---------------------------------------------------------------------------
// aggregate (gather, no atomics): one wave per node, lane = feature
//   S[n][0:64]   = x[n] + sum_j x[ce[j].x]
//   S[n][64:128] = sum_j edge_attr[ce[j].y]
// ---------------------------------------------------------------------------
__global__ __launch_bounds__(256) void aggregate(const float* __restrict__ x,
                                                 const float* __restrict__ ea,
                                                 const int* __restrict__ rpRow,
                                                 const int2* __restrict__ ce,
                                                 float* __restrict__ S,
                                                 float* __restrict__ cntRow) {
    int wid = (blockIdx.x * 256 + threadIdx.x) >> 6;
    int lane = threadIdx.x & 63;
    if (wid >= N_NODES) return;
    int jb = rpRow[wid], je = rpRow[wid + 1];
    float ax0 = x[(size_t)wid * 64 + lane], ax1 = 0.f, ax2 = 0.f, ax3 = 0.f;
    float ae0 = 0.f, ae1 = 0.f, ae2 = 0.f, ae3 = 0.f;
    int j = jb;
    for (; j + 3 < je; j += 4) {
        int2 c0 = ce[j], c1 = ce[j + 1], c2 = ce[j + 2], c3 = ce[j + 3];
        ax0 += x[(size_t)c0.x * 64 + lane];
        ax1 += x[(size_t)c1.x * 64 + lane];
        ax2 += x[(size_t)c2.x * 64 + lane];
        ax3 += x[(size_t)c3.x * 64 + lane];
        ae0 += ea[(size_t)c0.y * 64 + lane];
        ae1 += ea[(size_t)c1.y * 64 + lane];
        ae2 += ea[(size_t)c2.y * 64 + lane];
        ae3 += ea[(size_t)c3.y * 64 + lane];
    }
    for (; j < je; ++j) {
        int2 c = ce[j];
        ax0 += x[(size_t)c.x * 64 + lane];
        ae0 += ea[(size_t)c.y * 64 + lane];
    }
    S[(size_t)wid * 128 + lane] = (ax0 + ax1) + (ax2 + ax3);
    S[(size_t)wid * 128 + 64 + lane] = (ae0 + ae1) + (ae2 + ae3);
    if (lane == 0) cntRow[wid] = (float)(je - jb + 1);
}

// ---------------------------------------------------------------------------
// Fused GEMM: out = epilogue(A[N,128] @ W[128,NC])
// MODE 0: W = [W_node; W_edge] stacked, out = relu(acc/cnt + b_node + (1-1/cnt)*b_edge)
// MODE 1: out = relu(acc + b1)
// MODE 2: out = acc + b2
// LDS: Al stride 132 (16B-aligned rows, bank-conflict-free A reads);
// column map c = j*16 + tcol (conflict-free W reads, coalesced stores).
// ---------------------------------------------------------------------------
template <int NC, int MODE>
__global__ __launch_bounds__(256) void gemm_k(const float* __restrict__ A,
                                              const float* __restrict__ Wa,
                                              const float* __restrict__ Wb,
                                              const float* __restrict__ ba,
                                              const float* __restrict__ bb,
                                              const float* __restrict__ cnt,
                                              float* __restrict__ out) {
    constexpr int CPT = NC / 16;  // cols per thread
    __shared__ float Al[64][132];
    __shared__ float Wl[64][NC];
    const int tid = threadIdx.x;
    const int rb = blockIdx.x * 64;

    for (int idx = tid; idx < 64 * 32; idx += 256) {
        int r = idx >> 5, c4 = idx & 31;
        int gr = rb + r;
        float4 v = make_float4(0.f, 0.f, 0.f, 0.f);
        if (gr < N_NODES) v = *reinterpret_cast<const float4*>(A + (size_t)gr * 128 + c4 * 4);
        *reinterpret_cast<float4*>(&Al[r][c4 * 4]) = v;
    }

    const int trow = tid >> 4, tcol = tid & 15;
    float acc[4][CPT];
#pragma unroll
    for (int q = 0; q < 4; q++)
#pragma unroll
        for (int j = 0; j < CPT; j++) acc[q][j] = 0.f;

    for (int half = 0; half < 2; ++half) {
        __syncthreads();
        for (int idx = tid; idx < 64 * (NC / 4); idx += 256) {
            int k = idx / (NC / 4), c4 = idx % (NC / 4);
            int gk = half * 64 + k;
            const float* src;
            if constexpr (MODE == 0) {
                src = (gk < 64) ? (Wa + (size_t)gk * NC + c4 * 4)
                                : (Wb + (size_t)(gk - 64) * NC + c4 * 4);
            } else {
                src = Wa + (size_t)gk * NC + c4 * 4;
            }
            *reinterpret_cast<float4*>(&Wl[k][c4 * 4]) = *reinterpret_cast<const float4*>(src);
        }
        __syncthreads();
#pragma unroll 4
        for (int k = 0; k < 64; k++) {
            float a0 = Al[trow][half * 64 + k];
            float a1 = Al[trow + 16][half * 64 + k];
            float a2 = Al[trow + 32][half * 64 + k];
            float a3 = Al[trow + 48][half * 64 + k];
#pragma unroll
            for (int j = 0; j < CPT; j++) {
                float w = Wl[k][j * 16 + tcol];
                acc[0][j] += a0 * w;
                acc[1][j] += a1 * w;
                acc[2][j] += a2 * w;
                acc[3][j] += a3 * w;
            }
        }
    }

#pragma unroll
    for (int q = 0; q < 4; q++) {
        int gr = rb + trow + 16 * q;
        if (gr >= N_NODES) continue;
        float inv = 0.f;
        if constexpr (MODE == 0) inv = 1.0f / cnt[gr];
#pragma unroll
        for (int j = 0; j < CPT; j++) {
            int c = j * 16 + tcol;
            float v = acc[q][j];
            if constexpr (MODE == 0) {
                v = v * inv + ba[c] + (1.0f - inv) * bb[c];
                v = fmaxf(v, 0.f);
            } else if constexpr (MODE == 1) {
                v = fmaxf(v + ba[c], 0.f);
            } else {
                v = v + ba[c];
            }
            out[(size_t)gr * NC + c] = v;
        }
    }
}

// ---------------------------------------------------------------------------
// APPNP step: out[i] = 0.9*dinv_i^2*h[i] + sum_e w'*h[src] + 0.1*h0[i]
// (0.9 folded into w' at scatter time); one wave per node, lane = feature
// ---------------------------------------------------------------------------
__global__ __launch_bounds__(256) void appnp_step(const float* __restrict__ h,
                                                  const float* __restrict__ h0,
                                                  float* __restrict__ out,
                                                  const int* __restrict__ rp,
                                                  const int2* __restrict__ ew,
                                                  const float* __restrict__ dinv) {
    int wid = (blockIdx.x * 256 + threadIdx.x) >> 6;
    int lane = threadIdx.x & 63;
    if (wid >= N_NODES) return;
    float di = dinv[wid];
    float acc0 = (1.0f - ALPHA) * di * di * h[(size_t)wid * 64 + lane];
    float acc1 = 0.f, acc2 = 0.f, acc3 = 0.f;
    int e = rp[wid], eend = rp[wid + 1];
    for (; e + 3 < eend; e += 4) {
        int2 w0 = ew[e], w1 = ew[e + 1], w2 = ew[e + 2], w3 = ew[e + 3];
        acc0 += __int_as_float(w0.y) * h[(size_t)w0.x * 64 + lane];
        acc1 += __int_as_float(w1.y) * h[(size_t)w1.x * 64 + lane];
        acc2 += __int_as_float(w2.y) * h[(size_t)w2.x * 64 + lane];
        acc3 += __int_as_float(w3.y) * h[(size_t)w3.x * 64 + lane];
    }
    for (; e < eend; ++e) {
        int2 w = ew[e];
        acc0 += __int_as_float(w.y) * h[(size_t)w.x * 64 + lane];
    }
    out[(size_t)wid * 64 + lane] =
        ((acc0 + acc1) + (acc2 + acc3)) + ALPHA * h0[(size_t)wid * 64 + lane];
}

// ---------------------------------------------------------------------------
extern "C" void kernel_launch(void* const* d_in, const int* in_sizes, int n_in,
                              void* d_out, int out_size, void* d_ws, size_t ws_size,
                              hipStream_t stream) {
    const float* x      = (const float*)d_in[0];
    const float* eattr  = (const float*)d_in[1];
    const float* W_node = (const float*)d_in[2];
    const float* b_node = (const float*)d_in[3];
    const float* W_edge = (const float*)d_in[4];
    const float* b_edge = (const float*)d_in[5];
    const float* W1     = (const float*)d_in[6];
    const float* b1     = (const float*)d_in[7];
    const float* W2     = (const float*)d_in[8];
    const float* b2     = (const float*)d_in[9];
    const int*   ei     = (const int*)d_in[10];
    float* out = (float*)d_out;

    char* ws = (char*)d_ws;
    size_t off = 0;
    auto alloc = [&](size_t bytes) -> void* {
        void* p = ws + off;
        off += (bytes + 511) & ~(size_t)511;
        return p;
    };
    float* buf0   = (float*)alloc((size_t)N_NODES * 128 * 4);  // S / x_enh / h_mid / hA|hB
    float* h0     = (float*)alloc((size_t)N_NODES * 64 * 4);   // also hosts ce early
    int2*  ew     = (int2*)alloc((size_t)E_EDGES * 8);
    float* cntRow = (float*)alloc((size_t)N_NODES * 4);
    int*   zeros4 = (int*)alloc((size_t)4 * N_NODES * 4);      // degRow|degDst|curRow|curDst
    float* dinv   = (float*)alloc((size_t)N_NODES * 4);
    int*   rpRow  = (int*)alloc((size_t)(N_NODES + 1) * 4);
    int*   rpDst  = (int*)alloc((size_t)(N_NODES + 1) * 4);
    int*   blockSums = (int*)alloc(1024 * 4);
    int*   blockScan = (int*)alloc(1024 * 4);

    int* degRow = zeros4;
    int* degDst = zeros4 + N_NODES;
    int* curRow = zeros4 + 2 * N_NODES;
    int* curDst = zeros4 + 3 * N_NODES;

    // ce aliases the h0 region: dead before h0 is first written (gemm<64,2>)
    int2* ce = (int2*)h0;

    constexpr int NB = (N_NODES + 255) / 256;  // 391 scan chunks (< 512)

    hipMemsetAsync(zeros4, 0, (size_t)4 * N_NODES * 4, stream);

    hist2<<<(E_EDGES + 255) / 256, 256, 0, stream>>>(ei, degRow, degDst);
    dinv_kernel<<<(N_NODES + 255) / 256, 256, 0, stream>>>(degDst, dinv);

    scan_block_sums2<<<dim3(NB, 2), 256, 0, stream>>>(degRow, degDst, blockSums);
    scan_top2<<<2, 512, 0, stream>>>(blockSums, blockScan, NB);
    scan_write_rp2<<<dim3(NB, 2), 256, 0, stream>>>(degRow, degDst, blockScan, rpRow, rpDst);

    scatter_both<<<(E_EDGES + 255) / 256, 256, 0, stream>>>(ei, dinv, rpRow, rpDst,
                                                            curRow, curDst, ce, ew);

    aggregate<<<(N_NODES + 3) / 4, 256, 0, stream>>>(x, eattr, rpRow, ce, buf0, cntRow);

    gemm_k<128, 0><<<(N_NODES + 63) / 64, 256, 0, stream>>>(buf0, W_node, W_edge, b_node, b_edge, cntRow, buf0);
    gemm_k<128, 1><<<(N_NODES + 63) / 64, 256, 0, stream>>>(buf0, W1, nullptr, b1, nullptr, nullptr, buf0);
    gemm_k<64, 2><<<(N_NODES + 63) / 64, 256, 0, stream>>>(buf0, W2, nullptr, b2, nullptr, nullptr, h0);

    float* hA = buf0;
    float* hB = buf0 + (size_t)N_NODES * 64;
    const float* hcur = h0;
    for (int k = 0; k < K_ITERS; k++) {
        float* dst = (k == K_ITERS - 1) ? out : ((k & 1) ? hB : hA);
        appnp_step<<<(N_NODES * 64 + 255) / 256, 256, 0, stream>>>(hcur, h0, dst, rpDst, ew, dinv);
        hcur = dst;
    }
}